// Round 16
// baseline (397.295 us; speedup 1.0000x reference)
//
#include <hip/hip_runtime.h>
#include <hip/hip_bf16.h>
#include <math.h>

#define BDIM 4
#define TDIM 2048
#define CDIM 2048
#define HDIM 16
#define DDIM 128
#define MROWS (BDIM*TDIM)     /* 8192 */
#define NQKV (3*CDIM)         /* 6144 */
#define GK   CDIM             /* 2048 = K of both GEMMs */
#define QSZ  (MROWS*CDIM)

#define NTILES 32             /* GK/64 */
#define NITER  16             /* NTILES/2 */
#define RSZ    16384          /* shorts per region (A-half + B-half, 32KB) */
#define BH     8192           /* B-half offset within region (shorts) */

/* 1/sqrt(128) * log2(e): folded into W_qkv's Q rows at cvt time */
#define QSCALE 0.1275171f

typedef __attribute__((ext_vector_type(8))) short short8;
typedef __attribute__((ext_vector_type(4))) unsigned short ushort4v;
typedef __attribute__((ext_vector_type(4))) float f32x4;
typedef __attribute__((ext_vector_type(16))) float f32x16;

__device__ __forceinline__ unsigned short f2bf(float f) {
    unsigned int u = __float_as_uint(f);
    u += 0x7fffu + ((u >> 16) & 1u);        // RNE
    return (unsigned short)(u >> 16);
}

__device__ __forceinline__ unsigned int cvtpk_bf16(float lo, float hi) {
    unsigned int r;
    asm("v_cvt_pk_bf16_f32 %0, %1, %2" : "=v"(r) : "v"(lo), "v"(hi));
    return r;
}

__device__ __forceinline__ void gload16(const unsigned short* g, unsigned short* l) {
    __builtin_amdgcn_global_load_lds((__attribute__((address_space(1))) void*)(g),
                                     (__attribute__((address_space(3))) void*)(l),
                                     16, 0, 0);
}

// fused fp32 -> bf16 conversions for x, W_qkv (Q rows pre-scaled), W_out
__global__ __launch_bounds__(256) void cvt_all(const float* __restrict__ x,
                                               const float* __restrict__ wqkv,
                                               const float* __restrict__ wout,
                                               unsigned short* __restrict__ xb,
                                               unsigned short* __restrict__ wqkvb,
                                               unsigned short* __restrict__ woutb)
{
    const int stride = gridDim.x * blockDim.x;
    const int t0 = blockIdx.x * blockDim.x + threadIdx.x;
    for (int i = t0; i < MROWS*CDIM/4; i += stride) {
        float4 f = ((const float4*)x)[i];
        ushort4v u;
        u[0]=f2bf(f.x); u[1]=f2bf(f.y); u[2]=f2bf(f.z); u[3]=f2bf(f.w);
        ((ushort4v*)xb)[i] = u;
    }
    for (int i = t0; i < NQKV*CDIM/4; i += stride) {
        float4 f = ((const float4*)wqkv)[i];
        const float s = (i < CDIM*CDIM/4) ? QSCALE : 1.0f;   // scale W_q rows
        ushort4v u;
        u[0]=f2bf(f.x*s); u[1]=f2bf(f.y*s); u[2]=f2bf(f.z*s); u[3]=f2bf(f.w*s);
        ((ushort4v*)wqkvb)[i] = u;
    }
    for (int i = t0; i < CDIM*CDIM/4; i += stride) {
        float4 f = ((const float4*)wout)[i];
        ushort4v u;
        u[0]=f2bf(f.x); u[1]=f2bf(f.y); u[2]=f2bf(f.z); u[3]=f2bf(f.w);
        ((ushort4v*)woutb)[i] = u;
    }
}

// ---- 8-phase 256x256 bf16 NT GEMM, r16: hoisted addressing ---------------
// Ledger identical to r13/r15 (regions q0..q3 lag-6, vmcnt(8) even phases,
// single closing lgkm(0)+barrier). CHANGE: all per-phase addresses are now
// {hoisted per-thread base pointer} + {compile-time offset}:
//   LDS reads: region q at q*RSZ (A@+0, B@+BH); bases pAlo/pAhi/pBlo/pBhi
//     cover q<2 / q>=2 so every ds_read offset < 64KB (fits offset: field).
//   Global stages: pAg/pAgj/pBg/pBgj advance +=128/iter; last iter peeled
//     (removes the t2/t3 clamp from the steady-state loop).
// Motivation: r15 PMC shows VALUBusy 18.8% ~= 220 cyc/phase/SIMD of address
// recompute on the critical path (the only VALU in the loop).
template<int MQ, int Q, bool RDB, int WN>
__device__ __forceinline__ void gphase(
    const unsigned short* __restrict__ pAlo, const unsigned short* __restrict__ pAhi,
    const unsigned short* __restrict__ pBlo, const unsigned short* __restrict__ pBhi,
    const unsigned short* gsrc, const unsigned short* gsrcj, unsigned short* ldst,
    short8 (&bfr)[4], f32x4 (&acc)[8][4])
{
    const unsigned short* pA = (Q < 2) ? pAlo : pAhi;
    const unsigned short* pB = (Q < 2) ? pBlo : pBhi;
    constexpr int ro = (Q & 1) * RSZ;
    short8 af[4];
#pragma unroll
    for (int mi = 0; mi < 4; ++mi)
        af[mi] = *(const short8*)&pA[ro + (MQ*4 + mi)*512];
    if (RDB) {
#pragma unroll
        for (int nj = 0; nj < 4; ++nj)
            bfr[nj] = *(const short8*)&pB[ro + nj*512];
    }
    gload16(gsrc,  ldst);
    gload16(gsrcj, ldst + 512);
    if (WN == 8) asm volatile("s_waitcnt vmcnt(8)" ::: "memory");
    __builtin_amdgcn_s_setprio(1);
#pragma unroll
    for (int mi = 0; mi < 4; ++mi)
#pragma unroll
        for (int nj = 0; nj < 4; ++nj)
            acc[MQ*4 + mi][nj] = __builtin_amdgcn_mfma_f32_16x16x32_bf16(af[mi], bfr[nj], acc[MQ*4 + mi][nj], 0, 0, 0);
    __builtin_amdgcn_s_setprio(0);
    asm volatile("s_waitcnt lgkmcnt(0)" ::: "memory");
    __builtin_amdgcn_s_barrier();
}

template<int MODE, int RX>
__global__ __launch_bounds__(512, 2) void gemm8(const unsigned short* __restrict__ A,
                                                const unsigned short* __restrict__ B,
                                                float* __restrict__ outp,
                                                unsigned short* __restrict__ qb,
                                                unsigned short* __restrict__ kb,
                                                unsigned short* __restrict__ vt,
                                                int Nsz)
{
    extern __shared__ unsigned short lds[];   // 4 regions x 32KB = 128 KB
    const int tid  = threadIdx.x;
    const int w    = tid >> 6;
    const int lane = tid & 63;
    const int wr   = w >> 2, wc = w & 3;
    const int fr   = lane & 15;
    const int fg   = lane >> 4;
    const int colu = (fg ^ ((fr >> 1) & 3)) * 8;

    const int gx  = gridDim.x, gy = gridDim.y;
    const int id  = blockIdx.x + blockIdx.y * gx;
    const int xcd = id & 7;
    const int jj  = id >> 3;
    const int mx  = gx / RX;
    const int my  = (gy * RX) >> 3;
    const int bx  = (xcd % RX) * mx + (jj % mx);
    const int by  = (xcd / RX) * my + (jj / mx);
    const int m0  = bx * 256, n0 = by * 256;

    // hoisted LDS read bases (per-thread); every phase offset is compile-time
    const int rdA = (wr*128 + fr)*32 + colu;
    const int rdB = (wc*64  + fr)*32 + colu;
    const unsigned short* pAlo = lds + rdA;
    const unsigned short* pAhi = lds + 2*RSZ + rdA;
    const unsigned short* pBlo = lds + BH + rdB;
    const unsigned short* pBhi = lds + 2*RSZ + BH + rdB;

    // hoisted stage pointers: per-thread global src, per-wave LDS dst
    const int srow = lane >> 2;
    const int sw   = ((lane & 3) ^ ((lane >> 3) & 3)) * 8;
    const unsigned short* gA0  = A + (size_t)(m0 + w*32 + srow)*GK + sw;
    const unsigned short* gB0  = B + (size_t)(n0 + w*32 + srow)*GK + sw;
    const unsigned short* gA0j = gA0 + (size_t)16*GK;
    const unsigned short* gB0j = gB0 + (size_t)16*GK;
    unsigned short* dW = lds + w*1024;   // wave's slice within a half-tile

    f32x4 acc[8][4];
#pragma unroll
    for (int i = 0; i < 8; ++i)
#pragma unroll
        for (int j = 0; j < 4; ++j) acc[i][j] = (f32x4)(0.f);
    short8 bfr[4];

    // prologue: q0<-t0.lo, q1<-t0.hi, q2<-t1.lo
    gload16(gA0,      dW);              gload16(gA0j,      dW + 512);
    gload16(gB0,      dW + BH);         gload16(gB0j,      dW + BH + 512);
    gload16(gA0 + 32, dW + RSZ);        gload16(gA0j + 32, dW + RSZ + 512);
    gload16(gB0 + 32, dW + RSZ + BH);   gload16(gB0j + 32, dW + RSZ + BH + 512);
    gload16(gA0 + 64, dW + 2*RSZ);      gload16(gA0j + 64, dW + 2*RSZ + 512);
    gload16(gB0 + 64, dW + 2*RSZ + BH); gload16(gB0j + 64, dW + 2*RSZ + BH + 512);
    asm volatile("s_waitcnt vmcnt(0)" ::: "memory");
    __builtin_amdgcn_s_barrier();

    const unsigned short* pAg  = gA0;
    const unsigned short* pAgj = gA0j;
    const unsigned short* pBg  = gB0;
    const unsigned short* pBgj = gB0j;
    for (int i = 0; i < NITER - 1; ++i) {
        gphase<0,0,true ,0>(pAlo,pAhi,pBlo,pBhi, pAg+96,  pAgj+96,  dW+3*RSZ,      bfr, acc); // P1 rd q0, st A3<-t1.hi
        gphase<1,0,false,8>(pAlo,pAhi,pBlo,pBhi, pBg+96,  pBgj+96,  dW+3*RSZ+BH,   bfr, acc); // P2 rd q0, st B3
        gphase<0,1,true ,0>(pAlo,pAhi,pBlo,pBhi, pAg+128, pAgj+128, dW,            bfr, acc); // P3 rd q1, st A0<-t2.lo
        gphase<1,1,false,8>(pAlo,pAhi,pBlo,pBhi, pBg+128, pBgj+128, dW+BH,         bfr, acc); // P4 rd q1, st B0
        gphase<0,2,true ,0>(pAlo,pAhi,pBlo,pBhi, pAg+160, pAgj+160, dW+RSZ,        bfr, acc); // P5 rd q2, st A1<-t2.hi
        gphase<1,2,false,8>(pAlo,pAhi,pBlo,pBhi, pBg+160, pBgj+160, dW+RSZ+BH,     bfr, acc); // P6 rd q2, st B1
        gphase<0,3,true ,0>(pAlo,pAhi,pBlo,pBhi, pAg+192, pAgj+192, dW+2*RSZ,      bfr, acc); // P7 rd q3, st A2<-t3.lo
        gphase<1,3,false,8>(pAlo,pAhi,pBlo,pBhi, pBg+192, pBgj+192, dW+2*RSZ+BH,   bfr, acc); // P8 rd q3, st B2
        pAg += 128; pAgj += 128; pBg += 128; pBgj += 128;
    }
    // peeled last iteration: t1=31 still real; t2/t3 stages are dead (tile 0)
    gphase<0,0,true ,0>(pAlo,pAhi,pBlo,pBhi, pAg+96,  pAgj+96,  dW+3*RSZ,      bfr, acc);
    gphase<1,0,false,8>(pAlo,pAhi,pBlo,pBhi, pBg+96,  pBgj+96,  dW+3*RSZ+BH,   bfr, acc);
    gphase<0,1,true ,0>(pAlo,pAhi,pBlo,pBhi, gA0,     gA0j,     dW,            bfr, acc);
    gphase<1,1,false,8>(pAlo,pAhi,pBlo,pBhi, gB0,     gB0j,     dW+BH,         bfr, acc);
    gphase<0,2,true ,0>(pAlo,pAhi,pBlo,pBhi, gA0+32,  gA0j+32,  dW+RSZ,        bfr, acc);
    gphase<1,2,false,8>(pAlo,pAhi,pBlo,pBhi, gB0+32,  gB0j+32,  dW+RSZ+BH,     bfr, acc);
    gphase<0,3,true ,0>(pAlo,pAhi,pBlo,pBhi, gA0,     gA0j,     dW+2*RSZ,      bfr, acc);
    gphase<1,3,false,8>(pAlo,pAhi,pBlo,pBhi, gB0,     gB0j,     dW+2*RSZ+BH,   bfr, acc);
    asm volatile("s_waitcnt vmcnt(0)" ::: "memory");

    if (MODE == 0) {
#pragma unroll
        for (int mi = 0; mi < 8; ++mi)
#pragma unroll
            for (int nj = 0; nj < 4; ++nj) {
                const int n   = n0 + wc*64 + nj*16 + fr;
                const int sel = n >> 11;
                const int c   = n & 2047;
                const int hh  = c >> 7, dd = c & 127;
                const int mb  = m0 + wr*128 + mi*16 + fg*4;
                const int bb  = mb >> 11, tt = mb & 2047;
                if (sel == 2) {
                    ushort4v v;
#pragma unroll
                    for (int r = 0; r < 4; ++r) v[r] = f2bf(acc[mi][nj][r]);
                    *(ushort4v*)&vt[((size_t)(bb*HDIM + hh)*DDIM + dd)*TDIM + tt] = v;
                } else {
                    unsigned short* dstb = (sel == 0) ? qb : kb;
#pragma unroll
                    for (int r = 0; r < 4; ++r)
                        dstb[((size_t)(bb*HDIM + hh)*TDIM + tt + r)*DDIM + dd] = f2bf(acc[mi][nj][r]);
                }
            }
    } else {
#pragma unroll
        for (int mi = 0; mi < 8; ++mi)
#pragma unroll
            for (int nj = 0; nj < 4; ++nj) {
                const int n = n0 + wc*64 + nj*16 + fr;
#pragma unroll
                for (int r = 0; r < 4; ++r) {
                    const int m = m0 + wr*128 + mi*16 + fg*4 + r;
                    outp[(size_t)m*Nsz + n] = acc[mi][nj][r];
                }
            }
    }
}

// ---- Flash attention (byte-identical to round-11/13/15 version) -----------
__global__ __launch_bounds__(512) void attn_mfma(const unsigned short* __restrict__ Qg,
                                                 const unsigned short* __restrict__ Kg,
                                                 const unsigned short* __restrict__ Vt,
                                                 unsigned short* __restrict__ attb)
{
    extern __shared__ unsigned short smem[];
    unsigned short* KsB = smem;            // 2 x [64][128] (4-bit XOR swizzle)
    unsigned short* VsB = smem + 16384;    // 2 x [128][64] (3-bit XOR swizzle)

    const int tid  = threadIdx.x;
    const int w    = tid >> 6;             // 0..7
    const int lane = tid & 63;
    const int lq   = lane & 31;
    const int hi   = lane >> 5;
    const int bh   = blockIdx.x & 63;
    const int qb_  = 7 - (blockIdx.x >> 6);    // heavy blocks first
    const int q0   = qb_ * 256;
    const int qt   = 4*qb_ + 3;                // last 64-wide K-tile
    const int qw   = q0 + w*32;                // wave's first q row

    const unsigned short* Kbh  = Kg + (size_t)bh*TDIM*DDIM;
    const unsigned short* Vtbh = Vt + (size_t)bh*DDIM*TDIM;

    short8 qf[8];
    {
        const unsigned short* qrow = Qg + ((size_t)bh*TDIM + qw + lq)*DDIM + hi*8;
#pragma unroll
        for (int ds = 0; ds < 8; ++ds)
            qf[ds] = *(const short8*)(qrow + ds*16);
    }

    f32x16 oacc[4];
#pragma unroll
    for (int i = 0; i < 4; ++i) oacc[i] = (f32x16)(0.f);
    float m_r = -INFINITY, l_r = 0.f;

#define STAGE_K(buf, kt_)                                                        \
    {                                                                            \
        _Pragma("unroll")                                                        \
        for (int j = 0; j < 2; ++j) {                                            \
            const int rw  = (w<<3) + (j<<2) + (lane >> 4);                       \
            const int sub = (lane & 15) ^ (rw & 15);                             \
            gload16(Kbh + ((size_t)((kt_)*64 + rw))*DDIM + sub*8,                \
                    &KsB[(buf)*8192 + ((w<<3) + (j<<2))*128]);                   \
        }                                                                        \
    }
#define STAGE_V(buf, kt_)                                                        \
    {                                                                            \
        _Pragma("unroll")                                                        \
        for (int j = 0; j < 2; ++j) {                                            \
            const int d   = (w<<4) + (j<<3) + (lane >> 3);                       \
            const int sub = (lane & 7) ^ (d & 7);                                \
            gload16(Vtbh + (size_t)d*TDIM + (kt_)*64 + sub*8,                    \
                    &VsB[(buf)*8192 + ((w<<4) + (j<<3))*64]);                    \
        }                                                                        \
    }

    STAGE_K(0, 0);
    STAGE_V(0, 0);
    __syncthreads();

    for (int kt = 0; kt <= qt; ++kt) {
        const int cur = kt & 1;
        if (kt < qt) { STAGE_K(cur ^ 1, kt + 1); STAGE_V(cur ^ 1, kt + 1); }

#pragma unroll
        for (int ks2 = 0; ks2 < 2; ++ks2) {
            const int ktb = kt*64 + ks2*32;
            if (ktb <= qw + 31) {              // wave-uniform causal activity
                f32x16 sa = (f32x16)(0.f);
#pragma unroll
                for (int ds = 0; ds < 8; ++ds) {
                    const int kvl = ks2*32 + lq;
                    short8 kf = *(const short8*)&KsB[cur*8192 +
                        ((kvl*128 + ds*16 + hi*8) ^ ((kvl & 15) << 3))];
                    sa = __builtin_amdgcn_mfma_f32_32x32x16_bf16(kf, qf[ds], sa, 0, 0, 0);
                }

                if (ktb + 31 > qw) {
#pragma unroll
                    for (int r = 0; r < 16; ++r) {
                        const int kvg = ktb + (r&3) + 8*(r>>2) + 4*hi;
                        if (kvg > qw + lq) sa[r] = -INFINITY;
                    }
                }

                float p[16];
                bool slow = (kt == 0) && (ks2 == 0);
                if (!slow) {
#pragma unroll
                    for (int r = 0; r < 16; ++r) {
                        p[r] = exp2f(sa[r] - m_r);
                    }
                    float pm = p[0];
#pragma unroll
                    for (int r = 1; r < 16; ++r) pm = fmaxf(pm, p[r]);
                    slow = __any(pm > 256.0f);
                }
                if (slow) {
                    float mx = sa[0];
#pragma unroll
                    for (int r = 1; r < 16; ++r) mx = fmaxf(mx, sa[r]);
                    mx = fmaxf(mx, __shfl_xor(mx, 32));
                    const float mn = fmaxf(m_r, mx);
                    const float corr = exp2f(m_r - mn);
                    m_r = mn;
#pragma unroll
                    for (int r = 0; r < 16; ++r) p[r] = exp2f(sa[r] - m_r);
                    l_r *= corr;
#pragma unroll
                    for (int r = 0; r < 16; ++r) {
                        const float cr = __shfl(corr, (r&3) + 8*(r>>2) + 4*hi);
#pragma unroll
                        for (int dt = 0; dt < 4; ++dt) oacc[dt][r] *= cr;
                    }
                }

                float ls = 0.f;
#pragma unroll
                for (int r = 0; r < 16; ++r) ls += p[r];
                l_r += ls + __shfl_xor(ls, 32);

                short8 pa[2];
#pragma unroll
                for (int ks = 0; ks < 2; ++ks) {
                    const unsigned int wA = cvtpk_bf16(p[8*ks+0], p[8*ks+1]);
                    const unsigned int wB = cvtpk_bf16(p[8*ks+2], p[8*ks+3]);
                    const unsigned int wC = cvtpk_bf16(p[8*ks+4], p[8*ks+5]);
                    const unsigned int wD = cvtpk_bf16(p[8*ks+6], p[8*ks+7]);
                    const unsigned int u = __shfl_xor(hi ? wA : wC, 32);
                    const unsigned int v = __shfl_xor(hi ? wB : wD, 32);
                    unsigned int a0 = hi ? u  : wA;
                    unsigned int a1 = hi ? v  : wB;
                    unsigned int a2 = hi ? wC : u;
                    unsigned int a3 = hi ? wD : v;
                    unsigned int aw[4] = {a0, a1, a2, a3};
                    pa[ks] = *(short8*)aw;
                }

#pragma unroll
                for (int ks = 0; ks < 2; ++ks)
#pragma unroll
                    for (int dt = 0; dt < 4; ++dt) {
                        const int d = dt*32 + lq;
                        short8 vf = *(const short8*)&VsB[cur*8192 +
                            ((d*64 + ks2*32 + ks*16 + hi*8) ^ ((d & 7) << 3))];
                        oacc[dt] = __builtin_amdgcn_mfma_f32_32x32x16_bf16(pa[ks], vf, oacc[dt], 0, 0, 0);
                    }
            }
        }

        __syncthreads();
    }

    const float inv = 1.f / l_r;
    const int b = bh >> 4, h = bh & 15;
#pragma unroll
    for (int r = 0; r < 16; ++r) {
        const int qrw = (r&3) + 8*(r>>2) + 4*hi;
        const float invq = __shfl(inv, qrw);
        unsigned short* obase = attb + ((size_t)b*TDIM + qw + qrw)*CDIM + h*DDIM + lq;
#pragma unroll
        for (int dt = 0; dt < 4; ++dt)
            obase[dt*32] = f2bf(oacc[dt][r] * invq);
    }
}

extern "C" void kernel_launch(void* const* d_in, const int* in_sizes, int n_in,
                              void* d_out, int out_size, void* d_ws, size_t ws_size,
                              hipStream_t stream)
{
    const float* x    = (const float*)d_in[0];   // [B,T,C]
    const float* Wqkv = (const float*)d_in[1];   // [3C,C]
    const float* Wout = (const float*)d_in[2];   // [C,C]
    float* out = (float*)d_out;

    unsigned short* ws = (unsigned short*)d_ws;
    unsigned short* xb    = ws;
    unsigned short* Wqkvb = xb    + (size_t)MROWS*CDIM;
    unsigned short* Woutb = Wqkvb + (size_t)NQKV*CDIM;
    unsigned short* Qb    = Woutb + (size_t)CDIM*CDIM;    // [bh,t,d] (pre-scaled via W)
    unsigned short* Kb    = Qb + QSZ;                     // [bh,t,d]
    unsigned short* Vtb   = Kb + QSZ;                     // [bh,d,t]
    unsigned short* attb  = Vtb + QSZ;                    // [B,T,C]

    cvt_all<<<2048, 256, 0, stream>>>(x, Wqkv, Wout, xb, Wqkvb, Woutb);
    gemm8<0,4><<<dim3(MROWS/256, NQKV/256), 512, 131072, stream>>>(xb, Wqkvb, nullptr, Qb, Kb, Vtb, NQKV);
    attn_mfma<<<dim3(64*8), 512, 65536, stream>>>(Qb, Kb, Vtb, attb);
    gemm8<1,2><<<dim3(MROWS/256, CDIM/256), 512, 131072, stream>>>(attb, Woutb, out, nullptr, nullptr, nullptr, CDIM);
}